// Round 5
// baseline (23.086 us; speedup 1.0000x reference)
//
#include <hip/hip_runtime.h>
#include <hip/hip_bf16.h>

// SiameseConv: out[b,y,x,o] = sum_{i,j,c} det[b,y+i,x+j,c] * tmpl[b,i,j,c,o]
// det: [64,20,20,256] f32, tmpl: [64,4,4,256*20] f32, out: [64,17,17,20] f32.
//
// Per-example GEMM C[289x20] = A[289x4096] x B[4096x20], K=(ij,c), K-split by
// channel chunk of 32 -> 512 blocks; partials to d_ws + float4 reduce (R2:
// atomics were ~37us of cross-XCD contention).
// R5: (a) 256-thread blocks (4 waves): B-frag LDS re-reads halve (each wave
// amortizes B over ~5 M-tiles) -> grid ds_read_b128 328K->221K; (b) staging
// rewritten as fixed unrolled per-thread load batches (ILP, no divergent-trip
// grid-stride loops); (c) template o-pad 32->24 + clamped pad-col reads (no
// zero-fill) -> LDS 49KB -> 3 blocks/CU capacity.

typedef __bf16 bf16x8 __attribute__((ext_vector_type(8)));
typedef float f32x4 __attribute__((ext_vector_type(4)));

#define NB 64
#define C_TOT 256
#define CQ 32            // channels per block
#define NQ 8             // c-chunks
#define NPOS 400         // 20*20 det positions
#define NP 289           // 17*17 output positions
#define NO 20            // outputs per position
#define OPAD 24          // padded o rows in LDS
#define PTILE (NP * NO)  // 5780
#define DET_LDS_BYTES (NPOS * CQ * 2)       // 25600: [400 pos][32 c]
#define TMP_LDS_BYTES (16 * OPAD * CQ * 2)  // 24576: [16 ij][24 o][32 c]

__device__ __forceinline__ unsigned short bfbits(float f) {
  __bf16 h = (__bf16)f;
  return __builtin_bit_cast(unsigned short, h);
}

// out[e] = sum_{q} ws[q*369920 + e], float4-vectorized.
__global__ __launch_bounds__(256)
void reduce_kernel(const float4* __restrict__ ws, float4* __restrict__ out, int n4) {
  int i = blockIdx.x * 256 + threadIdx.x;
  if (i >= n4) return;
  float4 s = ws[i];
  #pragma unroll
  for (int q = 1; q < NQ; ++q) {
    float4 v = ws[q * n4 + i];
    s.x += v.x; s.y += v.y; s.z += v.z; s.w += v.w;
  }
  out[i] = s;
}

__device__ __forceinline__ void det_write(char* detB, int it, float4 v) {
  int pos = it >> 3, cg = it & 7;
  unsigned long long pk =
      (unsigned long long)bfbits(v.x) |
      ((unsigned long long)bfbits(v.y) << 16) |
      ((unsigned long long)bfbits(v.z) << 32) |
      ((unsigned long long)bfbits(v.w) << 48);
  // byte(pos,c) = pos*64 + (((c>>3) ^ ((pos>>1)&3))<<4) + (c&7)*2
  int byte = pos * 64 + (((cg >> 1) ^ ((pos >> 1) & 3)) << 4) + (cg & 1) * 8;
  *(unsigned long long*)(detB + byte) = pk;
}

__global__ __launch_bounds__(256, 3)
void siamese_kernel(const float* __restrict__ det,
                    const float* __restrict__ tmp,
                    float* __restrict__ ws) {
  __shared__ alignas(16) char lds[DET_LDS_BYTES + TMP_LDS_BYTES];
  char* detB = lds;
  char* tmpB = lds + DET_LDS_BYTES;

  const int tid = threadIdx.x;
  const int b   = blockIdx.x >> 3;
  const int q   = blockIdx.x & 7;
  const int c0  = q * CQ;

  const float* __restrict__ dsrc = det + (size_t)b * (NPOS * C_TOT) + c0;
  const float* __restrict__ tsrc = tmp + (size_t)b * (16 * C_TOT * NO);

  // ---- det staging: 3200 float4 items = 12/thread + tail(128) ----
  // Batch loads (independent, issued back-to-back), then cvt+ds_write.
  {
    float4 v[6];
    #pragma unroll
    for (int k = 0; k < 6; ++k) {
      int it = tid + k * 256;
      v[k] = *(const float4*)(dsrc + (it >> 3) * C_TOT + (it & 7) * 4);
    }
    #pragma unroll
    for (int k = 0; k < 6; ++k) det_write(detB, tid + k * 256, v[k]);
    #pragma unroll
    for (int k = 0; k < 6; ++k) {
      int it = tid + (k + 6) * 256;
      v[k] = *(const float4*)(dsrc + (it >> 3) * C_TOT + (it & 7) * 4);
    }
    float4 vt;
    if (tid < 128) {
      int it = 3072 + tid;
      vt = *(const float4*)(dsrc + (it >> 3) * C_TOT + (it & 7) * 4);
    }
    #pragma unroll
    for (int k = 0; k < 6; ++k) det_write(detB, tid + (k + 6) * 256, v[k]);
    if (tid < 128) det_write(detB, 3072 + tid, vt);
  }

  // ---- tmpl staging: 512 (ij,c) pairs = 2/thread; each pair = one 20-o row
  // (5 contiguous float4 = 80B) -> transpose via 20 ds_write_b16 into
  // [ij][o][c] with byte = ij*1536 + o*64 + (((c>>3)^((o>>1)&3))<<4)+(c&7)*2.
  {
    #pragma unroll
    for (int pp = 0; pp < 2; ++pp) {
      int pr = tid + pp * 256;
      int ij = pr >> 5, c = pr & 31;
      const float* s = tsrc + ij * (C_TOT * NO) + (c0 + c) * NO;
      float4 u[5];
      #pragma unroll
      for (int k = 0; k < 5; ++k) u[k] = *(const float4*)(s + k * 4);
      unsigned short sv[20];
      #pragma unroll
      for (int k = 0; k < 5; ++k) {
        sv[k*4+0] = bfbits(u[k].x); sv[k*4+1] = bfbits(u[k].y);
        sv[k*4+2] = bfbits(u[k].z); sv[k*4+3] = bfbits(u[k].w);
      }
      char* base = tmpB + ij * (OPAD * 64) + (c & 7) * 2;
      int g = (c >> 3) << 4;
      #pragma unroll
      for (int o = 0; o < NO; ++o) {
        int byte = o * 64 + (g ^ (((o >> 1) & 3) << 4));
        *(unsigned short*)(base + byte) = sv[o];
      }
    }
  }

  __syncthreads();

  // ---- compute: 19 M-tiles x 2 N-tiles over 4 waves, 16 K-steps of 32 ----
  const int w    = tid >> 6;
  const int lane = tid & 63;
  const int lo   = lane & 15;
  const int hi   = lane >> 4;
  const int nm   = (w < 3) ? 5 : 4;   // tiles m = w + 4*mi: 5/5/5/4

  int posb[5];
  #pragma unroll
  for (int mi = 0; mi < 5; ++mi) {
    int m = w + mi * 4;
    int p = m * 16 + lo;
    if (p > NP - 1) p = NP - 1;        // clamp pad rows (masked at store)
    posb[mi] = (p / 17) * 20 + (p % 17);
  }

  f32x4 acc[5][2] = {};

  const int o0r  = lo;
  const int o1r  = (16 + lo < OPAD) ? (16 + lo) : (OPAD - 1);  // clamp pad cols
  const int bad0 = o0r * 64 + ((hi ^ ((o0r >> 1) & 3)) << 4);
  const int bad1 = o1r * 64 + ((hi ^ ((o1r >> 1) & 3)) << 4);

  for (int ij = 0; ij < 16; ++ij) {
    const int sh = (ij >> 2) * 20 + (ij & 3);

    bf16x8 bf0 = *(const bf16x8*)(tmpB + bad0 + ij * (OPAD * 64));
    bf16x8 bf1 = *(const bf16x8*)(tmpB + bad1 + ij * (OPAD * 64));

    #pragma unroll
    for (int mi = 0; mi < 5; ++mi) {
      if (mi < nm) {
        int pos  = posb[mi] + sh;
        int byte = pos * 64 + ((hi ^ ((pos >> 1) & 3)) << 4);
        bf16x8 a = *(const bf16x8*)(detB + byte);
        acc[mi][0] = __builtin_amdgcn_mfma_f32_16x16x32_bf16(a, bf0, acc[mi][0], 0, 0, 0);
        acc[mi][1] = __builtin_amdgcn_mfma_f32_16x16x32_bf16(a, bf1, acc[mi][1], 0, 0, 0);
      }
    }
  }

  // ---- store partial tile (plain stores, no atomics) ----
  float* __restrict__ pws = ws + ((size_t)q * NB + b) * PTILE;
  #pragma unroll
  for (int mi = 0; mi < 5; ++mi) {
    if (mi < nm) {
      int m = w + mi * 4;
      #pragma unroll
      for (int n = 0; n < 2; ++n) {
        int o = n * 16 + lo;
        if (o < NO) {
          #pragma unroll
          for (int v = 0; v < 4; ++v) {
            int p = m * 16 + hi * 4 + v;   // C/D: row=(lane>>4)*4+reg, col=lane&15
            if (p < NP) pws[p * NO + o] = acc[mi][n][v];
          }
        }
      }
    }
  }
}

extern "C" void kernel_launch(void* const* d_in, const int* in_sizes, int n_in,
                              void* d_out, int out_size, void* d_ws, size_t ws_size,
                              hipStream_t stream) {
  (void)in_sizes; (void)n_in; (void)ws_size;
  const float* det = (const float*)d_in[0];
  const float* tmp = (const float*)d_in[1];
  float* out = (float*)d_out;
  float* ws  = (float*)d_ws;   // NQ * NB * PTILE * 4 = 11.8 MB partials

  siamese_kernel<<<dim3(NB * NQ), dim3(256), 0, stream>>>(det, tmp, ws);
  int n4 = out_size / 4;       // 369920/4 = 92480 float4, exact
  reduce_kernel<<<dim3((n4 + 255) / 256), dim3(256), 0, stream>>>(
      (const float4*)ws, (float4*)out, n4);
}

// Round 6
// 22.801 us; speedup vs baseline: 1.0125x; 1.0125x over previous
//
#include <hip/hip_runtime.h>
#include <hip/hip_bf16.h>

// SiameseConv: out[b,y,x,o] = sum_{i,j,c} det[b,y+i,x+j,c] * tmpl[b,i,j,c,o]
// det: [64,20,20,256] f32, tmpl: [64,4,4,256*20] f32, out: [64,17,17,20] f32.
//
// Per-example GEMM C[289x20] = A[289x4096] x B[4096x20], K=(ij,c), K-split by
// channel chunk of 32 -> 512 blocks; partials to d_ws + reduce (R2: atomics
// were ~37us cross-XCD). R6: attack INSTRUCTION ISSUE counts (R4/R5 nulls
// showed byte-level models wrong): tmpl transpose now in registers
// (cvt_pk + b128 writes: 10240 ds_write_b16 -> 1280 ds_write_b128), det
// staging 3328 b64 -> 1664 b128, epilogue float4 stores into transposed
// ws [q][b][o][p292] (6080 scalar -> ~1520 f4), reduce does the [o][p]->[p][o]
// transpose through LDS.

typedef __bf16 bf16x8 __attribute__((ext_vector_type(8)));
typedef float f32x4 __attribute__((ext_vector_type(4)));

#define NB 64
#define C_TOT 256
#define CQ 32            // channels per block
#define NQ 8             // c-chunks
#define NPOS 400         // 20*20 det positions
#define NP 289           // 17*17 output positions
#define NPP 292          // padded p stride (16B-aligned rows)
#define NO 20            // outputs per position
#define OPAD 24          // padded o rows in LDS tmpl tile
#define DET_LDS_BYTES (NPOS * CQ * 2)       // 25600: [400 pos][32 c]
#define TMP_LDS_BYTES (16 * OPAD * CQ * 2)  // 24576: [16 ij][24 o][32 c]

__device__ __forceinline__ unsigned short bfbits(float f) {
  __bf16 h = (__bf16)f;
  return __builtin_bit_cast(unsigned short, h);
}
__device__ __forceinline__ unsigned pk2(float a, float b) {
  return (unsigned)bfbits(a) | ((unsigned)bfbits(b) << 16);
}

// ---- reduce: out[b,p,o] = sum_q ws[q,b,o,p]; transpose via LDS ----
// grid: (b, p-group of 80) = 64*4 blocks, 256 threads.
__global__ __launch_bounds__(256)
void reduce_kernel(const float* __restrict__ ws, float* __restrict__ out) {
  __shared__ float sbuf[NO * 80];   // [o][80 p]
  const int b   = blockIdx.x >> 2;
  const int pg  = blockIdx.x & 3;
  const int p0g = pg * 80;
  const int np  = (NP - p0g < 80) ? (NP - p0g) : 80;   // 80,80,80,49
  const int nq4 = (np + 3) >> 2;                       // 20 or 13

  const int units = NO * nq4;
  for (int t = threadIdx.x; t < units; t += 256) {
    int o  = t / nq4;
    int pq = t - o * nq4;
    int pp = p0g + pq * 4;
    const float* src = ws + ((size_t)b * NO + o) * NPP + pp;
    f32x4 s = *(const f32x4*)src;
    #pragma unroll
    for (int q = 1; q < NQ; ++q) {
      f32x4 v = *(const f32x4*)(src + (size_t)q * (NB * NO * NPP));
      s += v;
    }
    *(f32x4*)(&sbuf[o * 80 + pq * 4]) = s;
  }
  __syncthreads();

  for (int p = threadIdx.x; p < np; p += 256) {
    float* dst = out + (size_t)b * (NP * NO) + (p0g + p) * NO;
    #pragma unroll
    for (int k = 0; k < 5; ++k) {
      f32x4 v;
      #pragma unroll
      for (int j = 0; j < 4; ++j) v[j] = sbuf[(k * 4 + j) * 80 + p];
      *(f32x4*)(dst + k * 4) = v;
    }
  }
}

__global__ __launch_bounds__(512, 2)
void siamese_kernel(const float* __restrict__ det,
                    const float* __restrict__ tmp,
                    float* __restrict__ ws) {
  __shared__ alignas(16) char lds[DET_LDS_BYTES + TMP_LDS_BYTES];
  char* detB = lds;
  char* tmpB = lds + DET_LDS_BYTES;

  const int tid = threadIdx.x;
  const int b   = blockIdx.x >> 3;
  const int q   = blockIdx.x & 7;
  const int c0  = q * CQ;

  const float* __restrict__ dsrc = det + (size_t)b * (NPOS * C_TOT) + c0;
  const float* __restrict__ tsrc = tmp + (size_t)b * (16 * C_TOT * NO);

  // ---- det staging: 1600 units (pos, c-octet cp); 2 float4 loads ->
  // 1 ds_write_b128. byte = pos*64 + ((cp ^ ((pos>>1)&3))<<4), c&7 in-granule.
  {
    #pragma unroll
    for (int k = 0; k < 3; ++k) {
      int u   = tid + k * 512;
      int pos = u >> 2, cp = u & 3;
      const float* s = dsrc + pos * C_TOT + cp * 8;
      float4 A = *(const float4*)s;
      float4 B = *(const float4*)(s + 4);
      uint4 w = { pk2(A.x, A.y), pk2(A.z, A.w), pk2(B.x, B.y), pk2(B.z, B.w) };
      *(uint4*)(detB + pos * 64 + ((cp ^ ((pos >> 1) & 3)) << 4)) = w;
    }
    if (tid < 64) {
      int u   = 1536 + tid;
      int pos = u >> 2, cp = u & 3;
      const float* s = dsrc + pos * C_TOT + cp * 8;
      float4 A = *(const float4*)s;
      float4 B = *(const float4*)(s + 4);
      uint4 w = { pk2(A.x, A.y), pk2(A.z, A.w), pk2(B.x, B.y), pk2(B.z, B.w) };
      *(uint4*)(detB + pos * 64 + ((cp ^ ((pos >> 1) & 3)) << 4)) = w;
    }
  }

  // ---- tmpl staging: 320 units (ij, c-octet co, o-quad oq). Load 8c x 4o
  // f32 (8 float4), register-transpose via cvt_pk, 4x ds_write_b128 into
  // swizzled [ij][o][c]: byte = ij*OPAD*64 + o*64 + ((co ^ ((o>>1)&3))<<4).
  if (tid < 320) {
    int ij = tid / 20;
    int r  = tid - ij * 20;
    int co = r / 5;
    int oq = r - co * 5;
    const float* s = tsrc + ij * (C_TOT * NO) + (c0 + co * 8) * NO + oq * 4;
    float4 v[8];
    #pragma unroll
    for (int rr = 0; rr < 8; ++rr) v[rr] = *(const float4*)(s + rr * NO);
    char* base = tmpB + ij * (OPAD * 64);
    #pragma unroll
    for (int k = 0; k < 4; ++k) {
      int o = oq * 4 + k;
      uint4 w;
      #define COMP(V) ((k == 0) ? (V).x : (k == 1) ? (V).y : (k == 2) ? (V).z : (V).w)
      w.x = pk2(COMP(v[0]), COMP(v[1]));
      w.y = pk2(COMP(v[2]), COMP(v[3]));
      w.z = pk2(COMP(v[4]), COMP(v[5]));
      w.w = pk2(COMP(v[6]), COMP(v[7]));
      #undef COMP
      *(uint4*)(base + o * 64 + ((co ^ ((o >> 1) & 3)) << 4)) = w;
    }
  }

  __syncthreads();

  // ---- compute: 19 M-tiles x 2 N-tiles over 8 waves, 16 K-steps of 32 ----
  const int w    = tid >> 6;
  const int lane = tid & 63;
  const int lo   = lane & 15;
  const int hi   = lane >> 4;
  const int nm   = (w < 3) ? 3 : 2;   // tiles m = w + 8*mi: 3/3/3/2x5 = 19

  int posb[3];
  #pragma unroll
  for (int mi = 0; mi < 3; ++mi) {
    int m = w + mi * 8;
    int p = m * 16 + lo;
    if (p > NP - 1) p = NP - 1;        // clamp pad rows (masked at store)
    posb[mi] = (p / 17) * 20 + (p % 17);
  }

  f32x4 acc[3][2] = {};

  const int o0r  = lo;
  const int o1r  = (16 + lo < OPAD) ? (16 + lo) : (OPAD - 1);  // clamp pad cols
  const int bad0 = o0r * 64 + ((hi ^ ((o0r >> 1) & 3)) << 4);
  const int bad1 = o1r * 64 + ((hi ^ ((o1r >> 1) & 3)) << 4);

  for (int ij = 0; ij < 16; ++ij) {
    const int sh = (ij >> 2) * 20 + (ij & 3);

    bf16x8 bf0 = *(const bf16x8*)(tmpB + bad0 + ij * (OPAD * 64));
    bf16x8 bf1 = *(const bf16x8*)(tmpB + bad1 + ij * (OPAD * 64));

    #pragma unroll
    for (int mi = 0; mi < 3; ++mi) {
      if (mi < nm) {
        int pos  = posb[mi] + sh;
        int byte = pos * 64 + ((hi ^ ((pos >> 1) & 3)) << 4);
        bf16x8 a = *(const bf16x8*)(detB + byte);
        acc[mi][0] = __builtin_amdgcn_mfma_f32_16x16x32_bf16(a, bf0, acc[mi][0], 0, 0, 0);
        acc[mi][1] = __builtin_amdgcn_mfma_f32_16x16x32_bf16(a, bf1, acc[mi][1], 0, 0, 0);
      }
    }
  }

  // ---- store partials as float4 into transposed ws[q][b][o][p292] ----
  // C/D frag: col(o)=lane&15, row(p)=(lane>>4)*4+reg -> reg v is contiguous p.
  float* __restrict__ pws = ws + ((size_t)q * NB + b) * (NO * NPP);
  #pragma unroll
  for (int mi = 0; mi < 3; ++mi) {
    if (mi < nm) {
      int p0 = (w + mi * 8) * 16 + hi * 4;
      #pragma unroll
      for (int n = 0; n < 2; ++n) {
        int o = n * 16 + lo;
        if (o < NO) {
          if (p0 + 4 <= NP) {
            *(f32x4*)(pws + o * NPP + p0) = acc[mi][n];
          } else if (p0 < NP) {
            #pragma unroll
            for (int v = 0; v < 4; ++v)
              if (p0 + v < NP) pws[o * NPP + p0 + v] = acc[mi][n][v];
          }
        }
      }
    }
  }
}

extern "C" void kernel_launch(void* const* d_in, const int* in_sizes, int n_in,
                              void* d_out, int out_size, void* d_ws, size_t ws_size,
                              hipStream_t stream) {
  (void)in_sizes; (void)n_in; (void)out_size; (void)ws_size;
  const float* det = (const float*)d_in[0];
  const float* tmp = (const float*)d_in[1];
  float* out = (float*)d_out;
  float* ws  = (float*)d_ws;   // 8 * 64 * 20 * 292 * 4B = 12.0 MB partials

  siamese_kernel<<<dim3(NB * NQ), dim3(512), 0, stream>>>(det, tmp, ws);
  reduce_kernel<<<dim3(NB * 4), dim3(256), 0, stream>>>(ws, out);
}

// Round 7
// 21.662 us; speedup vs baseline: 1.0657x; 1.0526x over previous
//
#include <hip/hip_runtime.h>
#include <hip/hip_bf16.h>

// SiameseConv: out[b,y,x,o] = sum_{i,j,c} det[b,y+i,x+j,c] * tmpl[b,i,j,c,o]
// det: [64,20,20,256] f32, tmpl: [64,4,4,256*20] f32, out: [64,17,17,20] f32.
//
// Per-example GEMM C[289x20] = A[289x4096] x B[4096x20], K=(ij,c), K-split by
// channel chunk of 32 -> 512 blocks; partials to d_ws + reduce (R2: atomics
// were ~37us cross-XCD). R7: bf16 partials (ws round-trip 24->12MB; reduce
// loads halved; err budget +0.3 vs threshold 6), OPAD 24->20 (LDS 46KB,
// pad-col reads clamp to real row 19), epilogue packs acc->bf16 uint2.

typedef __bf16 bf16x8 __attribute__((ext_vector_type(8)));
typedef float f32x4 __attribute__((ext_vector_type(4)));

#define NB 64
#define C_TOT 256
#define CQ 32            // channels per block
#define NQ 8             // c-chunks
#define NPOS 400         // 20*20 det positions
#define NP 289           // 17*17 output positions
#define NPP 296          // padded p stride in bf16 partials (8-elem aligned)
#define NO 20            // outputs per position
#define OPAD 20          // o rows in LDS tmpl tile
#define QSTRIDE (NB * NO * NPP)             // elems per q slice = 378880
#define DET_LDS_BYTES (NPOS * CQ * 2)       // 25600: [400 pos][32 c]
#define TMP_LDS_BYTES (16 * OPAD * CQ * 2)  // 20480: [16 ij][20 o][32 c]

__device__ __forceinline__ unsigned short bfbits(float f) {
  __bf16 h = (__bf16)f;
  return __builtin_bit_cast(unsigned short, h);
}
__device__ __forceinline__ unsigned pk2(float a, float b) {
  return (unsigned)bfbits(a) | ((unsigned)bfbits(b) << 16);
}
__device__ __forceinline__ float lo2f(unsigned u) {
  return __builtin_bit_cast(float, u << 16);
}
__device__ __forceinline__ float hi2f(unsigned u) {
  return __builtin_bit_cast(float, u & 0xFFFF0000u);
}

// ---- reduce: out[b,p,o] = sum_q bf16 ws[q,b,o,p]; transpose via LDS ----
// grid: (b, p-group of 80) = 64*4 blocks, 256 threads.
__global__ __launch_bounds__(256)
void reduce_kernel(const unsigned short* __restrict__ ws, float* __restrict__ out) {
  __shared__ float sbuf[NO * 80];   // [o][80 p]
  const int b    = blockIdx.x >> 2;
  const int pg   = blockIdx.x & 3;
  const int p0g  = pg * 80;
  const int np   = (NP - p0g < 80) ? (NP - p0g) : 80;   // 80,80,80,49
  const int noct = (np + 7) >> 3;                       // 10 or 7
  const int units = NO * noct;                          // 200 or 140

  const int t = threadIdx.x;
  if (t < units) {
    int o  = t / noct;
    int po = t - o * noct;
    const unsigned short* src = ws + ((size_t)b * NO + o) * NPP + p0g + po * 8;
    float s[8] = {0, 0, 0, 0, 0, 0, 0, 0};
    #pragma unroll
    for (int q = 0; q < NQ; ++q) {
      uint4 v = *(const uint4*)(src + (size_t)q * QSTRIDE);
      s[0] += lo2f(v.x); s[1] += hi2f(v.x);
      s[2] += lo2f(v.y); s[3] += hi2f(v.y);
      s[4] += lo2f(v.z); s[5] += hi2f(v.z);
      s[6] += lo2f(v.w); s[7] += hi2f(v.w);
    }
    #pragma unroll
    for (int j = 0; j < 8; ++j) sbuf[o * 80 + po * 8 + j] = s[j];
  }
  __syncthreads();

  for (int p = t; p < np; p += 256) {
    float* dst = out + (size_t)b * (NP * NO) + (p0g + p) * NO;
    #pragma unroll
    for (int k = 0; k < 5; ++k) {
      f32x4 v;
      #pragma unroll
      for (int j = 0; j < 4; ++j) v[j] = sbuf[(k * 4 + j) * 80 + p];
      *(f32x4*)(dst + k * 4) = v;
    }
  }
}

__global__ __launch_bounds__(512, 2)
void siamese_kernel(const float* __restrict__ det,
                    const float* __restrict__ tmp,
                    unsigned short* __restrict__ ws) {
  __shared__ alignas(16) char lds[DET_LDS_BYTES + TMP_LDS_BYTES];
  char* detB = lds;
  char* tmpB = lds + DET_LDS_BYTES;

  const int tid = threadIdx.x;
  const int b   = blockIdx.x >> 3;
  const int q   = blockIdx.x & 7;
  const int c0  = q * CQ;

  const float* __restrict__ dsrc = det + (size_t)b * (NPOS * C_TOT) + c0;
  const float* __restrict__ tsrc = tmp + (size_t)b * (16 * C_TOT * NO);

  // ---- det staging: 1600 units (pos, c-octet cp); 2 float4 loads ->
  // 1 ds_write_b128. byte = pos*64 + ((cp ^ ((pos>>1)&3))<<4).
  {
    #pragma unroll
    for (int k = 0; k < 3; ++k) {
      int u   = tid + k * 512;
      int pos = u >> 2, cp = u & 3;
      const float* s = dsrc + pos * C_TOT + cp * 8;
      float4 A = *(const float4*)s;
      float4 B = *(const float4*)(s + 4);
      uint4 w = { pk2(A.x, A.y), pk2(A.z, A.w), pk2(B.x, B.y), pk2(B.z, B.w) };
      *(uint4*)(detB + pos * 64 + ((cp ^ ((pos >> 1) & 3)) << 4)) = w;
    }
    if (tid < 64) {
      int u   = 1536 + tid;
      int pos = u >> 2, cp = u & 3;
      const float* s = dsrc + pos * C_TOT + cp * 8;
      float4 A = *(const float4*)s;
      float4 B = *(const float4*)(s + 4);
      uint4 w = { pk2(A.x, A.y), pk2(A.z, A.w), pk2(B.x, B.y), pk2(B.z, B.w) };
      *(uint4*)(detB + pos * 64 + ((cp ^ ((pos >> 1) & 3)) << 4)) = w;
    }
  }

  // ---- tmpl staging: 320 units (ij, c-octet co, o-quad oq). Load 8c x 4o,
  // register-transpose via cvt_pk, 4x ds_write_b128 into swizzled [ij][o][c]:
  // byte = ij*OPAD*64 + o*64 + ((co ^ ((o>>1)&3))<<4).
  if (tid < 320) {
    int ij = tid / 20;
    int r  = tid - ij * 20;
    int co = r / 5;
    int oq = r - co * 5;
    const float* s = tsrc + ij * (C_TOT * NO) + (c0 + co * 8) * NO + oq * 4;
    float4 v[8];
    #pragma unroll
    for (int rr = 0; rr < 8; ++rr) v[rr] = *(const float4*)(s + rr * NO);
    char* base = tmpB + ij * (OPAD * 64);
    #pragma unroll
    for (int k = 0; k < 4; ++k) {
      int o = oq * 4 + k;
      uint4 w;
      #define COMP(V) ((k == 0) ? (V).x : (k == 1) ? (V).y : (k == 2) ? (V).z : (V).w)
      w.x = pk2(COMP(v[0]), COMP(v[1]));
      w.y = pk2(COMP(v[2]), COMP(v[3]));
      w.z = pk2(COMP(v[4]), COMP(v[5]));
      w.w = pk2(COMP(v[6]), COMP(v[7]));
      #undef COMP
      *(uint4*)(base + o * 64 + ((co ^ ((o >> 1) & 3)) << 4)) = w;
    }
  }

  __syncthreads();

  // ---- compute: 19 M-tiles x 2 N-tiles over 8 waves, 16 K-steps of 32 ----
  const int w    = tid >> 6;
  const int lane = tid & 63;
  const int lo   = lane & 15;
  const int hi   = lane >> 4;
  const int nm   = (w < 3) ? 3 : 2;   // tiles m = w + 8*mi: 3/3/3/2x5 = 19

  int posb[3];
  #pragma unroll
  for (int mi = 0; mi < 3; ++mi) {
    int m = w + mi * 8;
    int p = m * 16 + lo;
    if (p > NP - 1) p = NP - 1;        // clamp pad rows (masked at store)
    posb[mi] = (p / 17) * 20 + (p % 17);
  }

  f32x4 acc[3][2] = {};

  const int o0r  = lo;
  const int o1r  = (16 + lo < NO) ? (16 + lo) : (NO - 1);  // clamp pad cols
  const int bad0 = o0r * 64 + ((hi ^ ((o0r >> 1) & 3)) << 4);
  const int bad1 = o1r * 64 + ((hi ^ ((o1r >> 1) & 3)) << 4);

  for (int ij = 0; ij < 16; ++ij) {
    const int sh = (ij >> 2) * 20 + (ij & 3);

    bf16x8 bf0 = *(const bf16x8*)(tmpB + bad0 + ij * (OPAD * 64));
    bf16x8 bf1 = *(const bf16x8*)(tmpB + bad1 + ij * (OPAD * 64));

    #pragma unroll
    for (int mi = 0; mi < 3; ++mi) {
      if (mi < nm) {
        int pos  = posb[mi] + sh;
        int byte = pos * 64 + ((hi ^ ((pos >> 1) & 3)) << 4);
        bf16x8 a = *(const bf16x8*)(detB + byte);
        acc[mi][0] = __builtin_amdgcn_mfma_f32_16x16x32_bf16(a, bf0, acc[mi][0], 0, 0, 0);
        acc[mi][1] = __builtin_amdgcn_mfma_f32_16x16x32_bf16(a, bf1, acc[mi][1], 0, 0, 0);
      }
    }
  }

  // ---- store partials as packed bf16 uint2 into ws[q][b][o][p296] ----
  // C/D frag: col(o)=lane&15, row(p)=(lane>>4)*4+reg -> reg v is contiguous p.
  unsigned short* __restrict__ pws = ws + ((size_t)q * NB + b) * (NO * NPP);
  #pragma unroll
  for (int mi = 0; mi < 3; ++mi) {
    if (mi < nm) {
      int p0 = (w + mi * 8) * 16 + hi * 4;
      #pragma unroll
      for (int n = 0; n < 2; ++n) {
        int o = n * 16 + lo;
        if (o < NO) {
          if (p0 + 4 <= NP) {
            uint2 val = { pk2(acc[mi][n][0], acc[mi][n][1]),
                          pk2(acc[mi][n][2], acc[mi][n][3]) };
            *(uint2*)(pws + o * NPP + p0) = val;
          } else if (p0 < NP) {   // p0 == 288: single last position
            pws[o * NPP + p0] = bfbits(acc[mi][n][0]);
          }
        }
      }
    }
  }
}

extern "C" void kernel_launch(void* const* d_in, const int* in_sizes, int n_in,
                              void* d_out, int out_size, void* d_ws, size_t ws_size,
                              hipStream_t stream) {
  (void)in_sizes; (void)n_in; (void)out_size; (void)ws_size;
  const float* det = (const float*)d_in[0];
  const float* tmp = (const float*)d_in[1];
  float* out = (float*)d_out;
  unsigned short* ws = (unsigned short*)d_ws;   // 8*64*20*296*2B = 6.06 MB

  siamese_kernel<<<dim3(NB * NQ), dim3(512), 0, stream>>>(det, tmp, ws);
  reduce_kernel<<<dim3(NB * 4), dim3(256), 0, stream>>>(ws, out);
}